// Round 1
// baseline (468.623 us; speedup 1.0000x reference)
//
#include <hip/hip_runtime.h>
#include <hip/hip_bf16.h>

// Problem constants: B=2, L=2048, D=1024, H=16, d_k=64
#define Hh 16
#define Ll 2048
#define Dd 1024
#define DK 64
#define Mm 4096  // B*L
#define Kk 1024
#define Nn 1024

typedef short bf16x8 __attribute__((ext_vector_type(8)));
typedef float f32x4 __attribute__((ext_vector_type(4)));

static __device__ __forceinline__ unsigned short f2bf(float f) {
    union { __hip_bfloat16 b; unsigned short u; } cv;
    cv.b = __float2bfloat16(f);
    return cv.u;
}

// ---------------- fp32 -> bf16 cast ----------------
__global__ __launch_bounds__(256) void cast_bf16(const float4* __restrict__ src,
                                                 ushort4* __restrict__ dst, int n4) {
    int i = blockIdx.x * blockDim.x + threadIdx.x;
    if (i >= n4) return;
    float4 v = src[i];
    ushort4 o;
    o.x = f2bf(v.x); o.y = f2bf(v.y); o.z = f2bf(v.z); o.w = f2bf(v.w);
    dst[i] = o;
}

// ---------------- GEMM: C = A @ W^T + bias ----------------
// A: [M,K] bf16 row-major. W: [N,K] bf16 row-major (nn.Linear weight).
// MODE 0: store bf16 to [B,H,L,64]   (Q/K projections)
// MODE 1: store bf16 to [B,H,64,L]   (V projection, transposed for PV MFMA B-operand)
// MODE 2: store fp32 row-major [M,N] (final output)
// 128x128 block tile, 4 waves of 64x64, BK=32, mfma_f32_16x16x32_bf16.
template <int MODE>
__global__ __launch_bounds__(256) void gemm_bt(const ushort* __restrict__ A,
                                               const ushort* __restrict__ W,
                                               const float* __restrict__ bias,
                                               void* __restrict__ out) {
    __shared__ __align__(16) ushort As[128 * 32];
    __shared__ __align__(16) ushort Bs[128 * 32];
    const int t = threadIdx.x;
    const int wave = t >> 6, lane = t & 63;
    const int quad = lane >> 4, l15 = lane & 15;
    const int brow = blockIdx.y * 128;  // M
    const int bcol = blockIdx.x * 128;  // N
    const int wr = (wave >> 1) * 64, wc = (wave & 1) * 64;

    f32x4 acc[4][4] = {};

    const int srow = t >> 1;            // 0..127
    const int scol = (t & 1) * 16;      // 0 or 16 (elements)

    for (int k0 = 0; k0 < Kk; k0 += 32) {
        const uint4* ga = (const uint4*)(A + (size_t)(brow + srow) * Kk + k0 + scol);
        const uint4* gw = (const uint4*)(W + (size_t)(bcol + srow) * Kk + k0 + scol);
        uint4 va0 = ga[0], va1 = ga[1];
        uint4 vw0 = gw[0], vw1 = gw[1];
        __syncthreads();  // protect previous iteration's fragment reads
        *(uint4*)(As + srow * 32 + scol)     = va0;
        *(uint4*)(As + srow * 32 + scol + 8) = va1;
        *(uint4*)(Bs + srow * 32 + scol)     = vw0;
        *(uint4*)(Bs + srow * 32 + scol + 8) = vw1;
        __syncthreads();

        bf16x8 af[4], bfr[4];
#pragma unroll
        for (int i = 0; i < 4; i++)
            af[i] = *(const bf16x8*)(As + (wr + i * 16 + l15) * 32 + quad * 8);
#pragma unroll
        for (int j = 0; j < 4; j++)
            bfr[j] = *(const bf16x8*)(Bs + (wc + j * 16 + l15) * 32 + quad * 8);
#pragma unroll
        for (int i = 0; i < 4; i++)
#pragma unroll
            for (int j = 0; j < 4; j++)
                acc[i][j] = __builtin_amdgcn_mfma_f32_16x16x32_bf16(af[i], bfr[j], acc[i][j], 0, 0, 0);
    }

    // Epilogue. C/D layout: lane l, reg r -> row = quad*4+r, col = l&15  [verified m89/m91]
#pragma unroll
    for (int i = 0; i < 4; i++) {
#pragma unroll
        for (int j = 0; j < 4; j++) {
            const int n = bcol + wc + j * 16 + l15;
            const float bv = bias[n];
#pragma unroll
            for (int r = 0; r < 4; r++) {
                const int m = brow + wr + i * 16 + quad * 4 + r;
                const float v = acc[i][j][r] + bv;
                if (MODE == 2) {
                    ((float*)out)[(size_t)m * Nn + n] = v;
                } else {
                    const int b = m >> 11, l = m & 2047;
                    const int h = n >> 6, dk = n & 63;
                    size_t idx;
                    if (MODE == 0)
                        idx = ((size_t)(b * Hh + h) * Ll + l) * DK + dk;
                    else
                        idx = ((size_t)(b * Hh + h) * DK + dk) * Ll + l;
                    ((ushort*)out)[idx] = f2bf(v);
                }
            }
        }
    }
}

// ---------------- fused attention (flash-style, online softmax) ----------------
// Q,K: [BH, L, 64] bf16.  Vt: [BH, 64, L] bf16.  Out: [B, L, H*64] bf16.
// Block: 256 threads = 4 waves; each wave owns 16 q-rows; K-tile = 32 keys.
__global__ __launch_bounds__(256) void attn_kernel(const ushort* __restrict__ Q,
                                                   const ushort* __restrict__ Kp,
                                                   const ushort* __restrict__ Vt,
                                                   ushort* __restrict__ Oout,
                                                   const int* __restrict__ masksize) {
    __shared__ __align__(16) ushort Ps[4][16 * 32];
    const int t = threadIdx.x;
    const int wave = t >> 6, lane = t & 63;
    const int quad = lane >> 4, l15 = lane & 15;
    const int blk = blockIdx.x;          // bh * (L/64) + qchunk
    const int bh = blk >> 5;             // L/64 = 32
    const int q0 = (blk & 31) * 64 + wave * 16;
    const int half = masksize[0] >> 1;

    const ushort* Qb = Q + (size_t)bh * Ll * DK;
    const ushort* Kb = Kp + (size_t)bh * Ll * DK;
    const ushort* Vb = Vt + (size_t)bh * DK * Ll;

    // Q A-fragments (fixed): lane holds Q[q0 + (l&15)][quad*8+j (+32)]
    const bf16x8 qf0 = *(const bf16x8*)(Qb + (size_t)(q0 + l15) * DK + quad * 8);
    const bf16x8 qf1 = *(const bf16x8*)(Qb + (size_t)(q0 + l15) * DK + 32 + quad * 8);

    f32x4 Of[4] = {};  // O[q=quad*4+r][d = i*16 + l15]
    float mrow[4], lrow[4];
#pragma unroll
    for (int r = 0; r < 4; r++) { mrow[r] = -1e30f; lrow[r] = 0.0f; }
    const float scale = 0.125f;  // 1/sqrt(64)

    for (int key0 = 0; key0 < Ll; key0 += 32) {
        // S = Q @ K_tile^T : two 16-key sub-tiles, 2 MFMAs each (k=0..31, 32..63)
        f32x4 S[2];
#pragma unroll
        for (int kb = 0; kb < 2; kb++) {
            const ushort* kr = Kb + (size_t)(key0 + kb * 16 + l15) * DK;
            bf16x8 kf0 = *(const bf16x8*)(kr + quad * 8);
            bf16x8 kf1 = *(const bf16x8*)(kr + 32 + quad * 8);
            f32x4 z = {};
            z = __builtin_amdgcn_mfma_f32_16x16x32_bf16(qf0, kf0, z, 0, 0, 0);
            z = __builtin_amdgcn_mfma_f32_16x16x32_bf16(qf1, kf1, z, 0, 0, 0);
            S[kb] = z;
        }

        // scale + float band mask (+1.0 inside window), per-row tile max
        float pl[2][4], tmax[4];
#pragma unroll
        for (int r = 0; r < 4; r++) {
            const int qi = q0 + quad * 4 + r;
            int d0 = qi - (key0 + l15);        d0 = d0 < 0 ? -d0 : d0;
            int d1 = qi - (key0 + 16 + l15);   d1 = d1 < 0 ? -d1 : d1;
            float s0 = S[0][r] * scale + (d0 <= half ? 1.0f : 0.0f);
            float s1 = S[1][r] * scale + (d1 <= half ? 1.0f : 0.0f);
            pl[0][r] = s0; pl[1][r] = s1;
            tmax[r] = fmaxf(s0, s1);
        }
#pragma unroll
        for (int off = 1; off < 16; off <<= 1)
#pragma unroll
            for (int r = 0; r < 4; r++)
                tmax[r] = fmaxf(tmax[r], __shfl_xor(tmax[r], off, 16));

        float alpha[4], rsum[4];
#pragma unroll
        for (int r = 0; r < 4; r++) {
            float mnew = fmaxf(mrow[r], tmax[r]);
            alpha[r] = __expf(mrow[r] - mnew);
            mrow[r] = mnew;
            float p0 = __expf(pl[0][r] - mnew);
            float p1 = __expf(pl[1][r] - mnew);
            pl[0][r] = p0; pl[1][r] = p1;
            rsum[r] = p0 + p1;
        }
#pragma unroll
        for (int off = 1; off < 16; off <<= 1)
#pragma unroll
            for (int r = 0; r < 4; r++)
                rsum[r] += __shfl_xor(rsum[r], off, 16);
#pragma unroll
        for (int r = 0; r < 4; r++) lrow[r] = alpha[r] * lrow[r] + rsum[r];

        // P: C-layout -> LDS -> A-operand layout (bf16)
        ushort* ps = &Ps[wave][0];
#pragma unroll
        for (int kb = 0; kb < 2; kb++)
#pragma unroll
            for (int r = 0; r < 4; r++)
                ps[(quad * 4 + r) * 32 + kb * 16 + l15] = f2bf(pl[kb][r]);
        __syncthreads();
        const bf16x8 pf = *(const bf16x8*)(ps + l15 * 32 + quad * 8);

        // O = alpha*O + P @ V_tile  (V B-operand from Vt rows: contiguous)
#pragma unroll
        for (int i = 0; i < 4; i++) {
            const bf16x8 vf = *(const bf16x8*)(Vb + (size_t)(i * 16 + l15) * Ll + key0 + quad * 8);
            f32x4 o = Of[i];
#pragma unroll
            for (int r = 0; r < 4; r++) o[r] *= alpha[r];
            Of[i] = __builtin_amdgcn_mfma_f32_16x16x32_bf16(pf, vf, o, 0, 0, 0);
        }
        __syncthreads();  // protect Ps before next iteration's writes
    }

    // epilogue: normalize and store bf16 to [B, L, H*64]
    const int b = bh >> 4, h = bh & 15;
#pragma unroll
    for (int i = 0; i < 4; i++) {
#pragma unroll
        for (int r = 0; r < 4; r++) {
            const int qi = q0 + quad * 4 + r;
            const float v = Of[i][r] / lrow[r];
            const size_t idx = ((size_t)b * Ll + qi) * Dd + h * DK + i * 16 + l15;
            Oout[idx] = f2bf(v);
        }
    }
}

// ---------------- launch ----------------
extern "C" void kernel_launch(void* const* d_in, const int* in_sizes, int n_in,
                              void* d_out, int out_size, void* d_ws, size_t ws_size,
                              hipStream_t stream) {
    const float* query = (const float*)d_in[0];
    const float* key   = (const float*)d_in[1];
    const float* value = (const float*)d_in[2];
    const float* Wq = (const float*)d_in[3];
    const float* bq = (const float*)d_in[4];
    const float* Wk = (const float*)d_in[5];
    const float* bk = (const float*)d_in[6];
    const float* Wv = (const float*)d_in[7];
    const float* bv = (const float*)d_in[8];
    const float* Wo = (const float*)d_in[9];
    const float* bo = (const float*)d_in[10];
    const int* masksize = (const int*)d_in[11];

    char* ws = (char*)d_ws;
    const size_t MB = 1024 * 1024;
    ushort* qb  = (ushort*)(ws + 0 * MB);   // [4096,1024] bf16
    ushort* kbf = (ushort*)(ws + 8 * MB);
    ushort* vbf = (ushort*)(ws + 16 * MB);
    ushort* wqb = (ushort*)(ws + 24 * MB);  // [1024,1024] bf16
    ushort* wkb = (ushort*)(ws + 26 * MB);
    ushort* wvb = (ushort*)(ws + 28 * MB);
    ushort* wob = (ushort*)(ws + 30 * MB);
    ushort* Qp  = (ushort*)(ws + 32 * MB);  // [BH, L, 64]
    ushort* Kp  = (ushort*)(ws + 40 * MB);  // [BH, L, 64]
    ushort* Vt  = (ushort*)(ws + 48 * MB);  // [BH, 64, L]
    ushort* AO  = (ushort*)(ws + 56 * MB);  // [4096, 1024]

    const int n4_big = Mm * Kk / 4;   // 1048576
    const int n4_w   = Kk * Nn / 4;   // 262144
    cast_bf16<<<n4_big / 256, 256, 0, stream>>>((const float4*)query, (ushort4*)qb, n4_big);
    cast_bf16<<<n4_big / 256, 256, 0, stream>>>((const float4*)key,   (ushort4*)kbf, n4_big);
    cast_bf16<<<n4_big / 256, 256, 0, stream>>>((const float4*)value, (ushort4*)vbf, n4_big);
    cast_bf16<<<n4_w / 256, 256, 0, stream>>>((const float4*)Wq, (ushort4*)wqb, n4_w);
    cast_bf16<<<n4_w / 256, 256, 0, stream>>>((const float4*)Wk, (ushort4*)wkb, n4_w);
    cast_bf16<<<n4_w / 256, 256, 0, stream>>>((const float4*)Wv, (ushort4*)wvb, n4_w);
    cast_bf16<<<n4_w / 256, 256, 0, stream>>>((const float4*)Wo, (ushort4*)wob, n4_w);

    dim3 ggrid(Nn / 128, Mm / 128);  // (8, 32)
    gemm_bt<0><<<ggrid, 256, 0, stream>>>(qb,  wqb, bq, (void*)Qp);
    gemm_bt<0><<<ggrid, 256, 0, stream>>>(kbf, wkb, bk, (void*)Kp);
    gemm_bt<1><<<ggrid, 256, 0, stream>>>(vbf, wvb, bv, (void*)Vt);

    attn_kernel<<<1024, 256, 0, stream>>>(Qp, Kp, Vt, AO, masksize);

    gemm_bt<2><<<ggrid, 256, 0, stream>>>(AO, wob, bo, d_out);
}